// Round 1
// baseline (1252.527 us; speedup 1.0000x reference)
//
#include <hip/hip_runtime.h>
#include <hip/hip_bf16.h>

// Problem constants (from reference setup_inputs)
#define F_SIZE 1024
#define E_DIM  128
#define N_D    6000
#define N_SE   1000
#define N_TOT  7000
#define M_TPL  300000
#define LAMB   1e-6f
#define SPLITK 4

__device__ __forceinline__ float hshrink(float v) {
    return fabsf(v) > LAMB ? v : 0.0f;
}

// ---------------------------------------------------------------------------
// Big GEMM with split-K: Cpart[sp][row][e] = sum_{k in chunk sp} A[row][k]*B[k][e]
// A: [MROWS][KDIM] row-major, B: [KDIM][128] row-major.
// Tile: BM=64, BN=128, BK=16; 256 threads; 8m x 4n per-thread register tile.
// grid = (ceil(MROWS/64), SPLITK)
// ---------------------------------------------------------------------------
template <int MROWS, int KDIM>
__global__ __launch_bounds__(256) void gemm_big(const float* __restrict__ A,
                                                const float* __restrict__ B,
                                                float* __restrict__ Cpart) {
    constexpr int BM = 64, BN = 128, BK = 16;
    constexpr int KT = (KDIM + BK - 1) / BK;  // total k-tiles
    __shared__ float As[BK][BM];   // k-major
    __shared__ float Bs[BK][BN];

    const int tid = threadIdx.x;
    const int tn  = tid & 31;   // n-group: 4 cols each
    const int tm  = tid >> 5;   // m-group: 8 rows each
    const int row0 = blockIdx.x * BM;
    const int sp   = blockIdx.y;
    const int kt0 = (sp * KT) / SPLITK;
    const int kt1 = ((sp + 1) * KT) / SPLITK;

    float acc[8][4];
#pragma unroll
    for (int i = 0; i < 8; i++)
#pragma unroll
        for (int j = 0; j < 4; j++) acc[i][j] = 0.0f;

    // A-tile load mapping: 64 rows x 16 k = 256 float4, one per thread
    const int lr = tid >> 2;          // 0..63
    const int lk = (tid & 3) * 4;     // 0,4,8,12
    const int grow = row0 + lr;

    for (int kt = kt0; kt < kt1; kt++) {
        const int k0 = kt * BK;
        __syncthreads();
        // ---- A tile -> LDS (k-major) ----
        float4 av = make_float4(0.f, 0.f, 0.f, 0.f);
        if (grow < MROWS && (k0 + lk) < KDIM)
            av = *(const float4*)(A + (size_t)grow * KDIM + (k0 + lk));
        As[lk + 0][lr] = av.x;
        As[lk + 1][lr] = av.y;
        As[lk + 2][lr] = av.z;
        As[lk + 3][lr] = av.w;
        // ---- B tile -> LDS: 16x128 = 512 float4, two per thread ----
        {
            int f  = tid;
            int bk = f >> 5, bn = (f & 31) * 4;
            float4 bv = make_float4(0.f, 0.f, 0.f, 0.f);
            if (k0 + bk < KDIM)
                bv = *(const float4*)(B + (size_t)(k0 + bk) * BN + bn);
            *(float4*)&Bs[bk][bn] = bv;
            f  = tid + 256;
            bk = f >> 5; bn = (f & 31) * 4;
            bv = make_float4(0.f, 0.f, 0.f, 0.f);
            if (k0 + bk < KDIM)
                bv = *(const float4*)(B + (size_t)(k0 + bk) * BN + bn);
            *(float4*)&Bs[bk][bn] = bv;
        }
        __syncthreads();
        // ---- compute ----
#pragma unroll
        for (int k = 0; k < BK; k++) {
            float4 a0 = *(const float4*)&As[k][tm * 8];
            float4 a1 = *(const float4*)&As[k][tm * 8 + 4];
            float4 bv = *(const float4*)&Bs[k][tn * 4];
            float a[8] = {a0.x, a0.y, a0.z, a0.w, a1.x, a1.y, a1.z, a1.w};
            float b[4] = {bv.x, bv.y, bv.z, bv.w};
#pragma unroll
            for (int i = 0; i < 8; i++)
#pragma unroll
                for (int j = 0; j < 4; j++) acc[i][j] += a[i] * b[j];
        }
    }

    float* outp = Cpart + (size_t)sp * MROWS * BN;
#pragma unroll
    for (int i = 0; i < 8; i++) {
        int r = row0 + tm * 8 + i;
        if (r < MROWS) {
            float4 v = make_float4(acc[i][0], acc[i][1], acc[i][2], acc[i][3]);
            *(float4*)(outp + (size_t)r * BN + tn * 4) = v;
        }
    }
}

// ---------------------------------------------------------------------------
// Small GEMM (K=128) that fuses the split-K reduction of its A input:
//   Ain[r][k] = pre( sum_s parts[s][r][k] )    pre: optional +preBias then relu
//   out[r][e] = act( sum_k Ain[r][k]*W[k][e] + bias[e] )   act: 0=relu 1=hshrink
// ---------------------------------------------------------------------------
__global__ __launch_bounds__(256) void gemm_small(const float* __restrict__ parts,
                                                  int nparts, size_t partStride,
                                                  const float* __restrict__ preBias,
                                                  const float* __restrict__ W,
                                                  const float* __restrict__ bias,
                                                  float* __restrict__ outp,
                                                  int Mrows, int act) {
    constexpr int BM = 64, BN = 128, BK = 16, KD = 128;
    __shared__ float As[BK][BM];
    __shared__ float Bs[BK][BN];

    const int tid = threadIdx.x;
    const int tn  = tid & 31;
    const int tm  = tid >> 5;
    const int row0 = blockIdx.x * BM;

    float acc[8][4];
#pragma unroll
    for (int i = 0; i < 8; i++)
#pragma unroll
        for (int j = 0; j < 4; j++) acc[i][j] = 0.0f;

    const int lr = tid >> 2;
    const int lk = (tid & 3) * 4;
    const int grow = row0 + lr;

    for (int kt = 0; kt < KD / BK; kt++) {
        const int k0 = kt * BK;
        __syncthreads();
        // A tile: sum partials (+ optional bias+relu)
        float4 av = make_float4(0.f, 0.f, 0.f, 0.f);
        if (grow < Mrows) {
            for (int s = 0; s < nparts; s++) {
                float4 p = *(const float4*)(parts + (size_t)s * partStride +
                                            (size_t)grow * KD + (k0 + lk));
                av.x += p.x; av.y += p.y; av.z += p.z; av.w += p.w;
            }
            if (preBias != nullptr) {
                float4 pb = *(const float4*)(preBias + k0 + lk);
                av.x = fmaxf(av.x + pb.x, 0.f);
                av.y = fmaxf(av.y + pb.y, 0.f);
                av.z = fmaxf(av.z + pb.z, 0.f);
                av.w = fmaxf(av.w + pb.w, 0.f);
            }
        }
        As[lk + 0][lr] = av.x;
        As[lk + 1][lr] = av.y;
        As[lk + 2][lr] = av.z;
        As[lk + 3][lr] = av.w;
        // B tile
        {
            int f  = tid;
            int bk = f >> 5, bn = (f & 31) * 4;
            *(float4*)&Bs[bk][bn] = *(const float4*)(W + (size_t)(k0 + bk) * BN + bn);
            f  = tid + 256;
            bk = f >> 5; bn = (f & 31) * 4;
            *(float4*)&Bs[bk][bn] = *(const float4*)(W + (size_t)(k0 + bk) * BN + bn);
        }
        __syncthreads();
#pragma unroll
        for (int k = 0; k < BK; k++) {
            float4 a0 = *(const float4*)&As[k][tm * 8];
            float4 a1 = *(const float4*)&As[k][tm * 8 + 4];
            float4 bv = *(const float4*)&Bs[k][tn * 4];
            float a[8] = {a0.x, a0.y, a0.z, a0.w, a1.x, a1.y, a1.z, a1.w};
            float b[4] = {bv.x, bv.y, bv.z, bv.w};
#pragma unroll
            for (int i = 0; i < 8; i++)
#pragma unroll
                for (int j = 0; j < 4; j++) acc[i][j] += a[i] * b[j];
        }
    }

    float4 bv = *(const float4*)(bias + tn * 4);
    float bb[4] = {bv.x, bv.y, bv.z, bv.w};
#pragma unroll
    for (int i = 0; i < 8; i++) {
        int r = row0 + tm * 8 + i;
        if (r < Mrows) {
            float v[4];
#pragma unroll
            for (int j = 0; j < 4; j++) {
                float u = acc[i][j] + bb[j];
                v[j] = act == 0 ? fmaxf(u, 0.f) : hshrink(u);
            }
            *(float4*)(outp + (size_t)r * BN + tn * 4) =
                make_float4(v[0], v[1], v[2], v[3]);
        }
    }
}

// ---------------------------------------------------------------------------
// Copy embSe into x rows [N_D, N_TOT)
// ---------------------------------------------------------------------------
__global__ void emb_copy(const float* __restrict__ embSe, float* __restrict__ x) {
    int i = blockIdx.x * blockDim.x + threadIdx.x;  // float4 index
    if (i < N_SE * E_DIM / 4)
        ((float4*)(x + (size_t)N_D * E_DIM))[i] = ((const float4*)embSe)[i];
}

// ---------------------------------------------------------------------------
// Head: per 64-triple tile, gather H[64][384] (rsqrtdeg-scaled x rows),
// U = H @ Wp1 + bp1 -> hardshrink -> dot Wp2 + bp2 -> hardshrink -> out[m]
// ---------------------------------------------------------------------------
__global__ __launch_bounds__(256) void final_mlp(const float* __restrict__ X,
                                                 const int* __restrict__ tpl,
                                                 const float* __restrict__ rsd,
                                                 const float* __restrict__ Wp1,
                                                 const float* __restrict__ bp1,
                                                 const float* __restrict__ Wp2,
                                                 const float* __restrict__ bp2,
                                                 float* __restrict__ outp) {
    constexpr int TM = 64, BN = 128, BK = 16, KD = 384;
    __shared__ float As[BK][TM];
    __shared__ float Bs[BK][BN];
    __shared__ int   ridx[TM][3];
    __shared__ float rscale[TM][3];

    const int tid = threadIdx.x;
    const int tn  = tid & 31;
    const int tm  = tid >> 5;
    const int m0  = blockIdx.x * TM;

    // stage triple indices + scales
    if (tid < TM * 3) {
        int m = tid / 3, s = tid % 3;
        int gm = m0 + m;
        int r = 0;
        float sc = 0.f;
        if (gm < M_TPL) {
            r  = tpl[gm * 3 + s];
            sc = rsd[r];
        }
        ridx[m][s]   = r;
        rscale[m][s] = sc;
    }

    float acc[8][4];
#pragma unroll
    for (int i = 0; i < 8; i++)
#pragma unroll
        for (int j = 0; j < 4; j++) acc[i][j] = 0.0f;

    const int lr = tid >> 2;
    const int lk = (tid & 3) * 4;

    for (int kt = 0; kt < KD / BK; kt++) {
        const int seg  = kt >> 3;          // which of the 3 gathered rows
        const int col0 = (kt & 7) * 16;    // column within x row
        __syncthreads();                   // iter 0: also covers ridx staging
        // gather A tile
        {
            int   r  = ridx[lr][seg];
            float sc = rscale[lr][seg];
            float4 v = *(const float4*)(X + (size_t)r * E_DIM + col0 + lk);
            As[lk + 0][lr] = v.x * sc;
            As[lk + 1][lr] = v.y * sc;
            As[lk + 2][lr] = v.z * sc;
            As[lk + 3][lr] = v.w * sc;
        }
        // B tile: Wp1 rows [kt*16, kt*16+16)
        {
            const int k0 = kt * BK;
            int f  = tid;
            int bk = f >> 5, bn = (f & 31) * 4;
            *(float4*)&Bs[bk][bn] = *(const float4*)(Wp1 + (size_t)(k0 + bk) * BN + bn);
            f  = tid + 256;
            bk = f >> 5; bn = (f & 31) * 4;
            *(float4*)&Bs[bk][bn] = *(const float4*)(Wp1 + (size_t)(k0 + bk) * BN + bn);
        }
        __syncthreads();
#pragma unroll
        for (int k = 0; k < BK; k++) {
            float4 a0 = *(const float4*)&As[k][tm * 8];
            float4 a1 = *(const float4*)&As[k][tm * 8 + 4];
            float4 bv = *(const float4*)&Bs[k][tn * 4];
            float a[8] = {a0.x, a0.y, a0.z, a0.w, a1.x, a1.y, a1.z, a1.w};
            float b[4] = {bv.x, bv.y, bv.z, bv.w};
#pragma unroll
            for (int i = 0; i < 8; i++)
#pragma unroll
                for (int j = 0; j < 4; j++) acc[i][j] += a[i] * b[j];
        }
    }

    // epilogue: u = HS(acc + bp1); partial = sum_e u*Wp2[e]; reduce over tn lanes
    float4 b1v = *(const float4*)(bp1 + tn * 4);
    float4 w2v = *(const float4*)(Wp2 + tn * 4);
    float  b2v = bp2[0];
#pragma unroll
    for (int i = 0; i < 8; i++) {
        float s = 0.f;
        s += hshrink(acc[i][0] + b1v.x) * w2v.x;
        s += hshrink(acc[i][1] + b1v.y) * w2v.y;
        s += hshrink(acc[i][2] + b1v.z) * w2v.z;
        s += hshrink(acc[i][3] + b1v.w) * w2v.w;
#pragma unroll
        for (int off = 1; off < 32; off <<= 1) s += __shfl_xor(s, off, 64);
        if (tn == 0) {
            int gm = m0 + tm * 8 + i;
            if (gm < M_TPL) outp[gm] = hshrink(s + b2v);
        }
    }
}

// ---------------------------------------------------------------------------
extern "C" void kernel_launch(void* const* d_in, const int* in_sizes, int n_in,
                              void* d_out, int out_size, void* d_ws, size_t ws_size,
                              hipStream_t stream) {
    const float* drugF = (const float*)d_in[0];
    const float* A     = (const float*)d_in[1];
    const int*   tpl   = (const int*)d_in[2];
    const float* rsd   = (const float*)d_in[3];
    const float* W1    = (const float*)d_in[4];
    const float* b1    = (const float*)d_in[5];
    const float* W2    = (const float*)d_in[6];
    const float* b2    = (const float*)d_in[7];
    const float* embSe = (const float*)d_in[8];
    const float* Wl    = (const float*)d_in[9];
    const float* bl    = (const float*)d_in[10];
    const float* Wp1   = (const float*)d_in[11];
    const float* bp1   = (const float*)d_in[12];
    const float* Wp2   = (const float*)d_in[13];
    const float* bp2   = (const float*)d_in[14];
    float* outp = (float*)d_out;

    float* ws    = (float*)d_ws;
    float* x     = ws;                         // N_TOT * 128 floats
    float* parts = ws + (size_t)N_TOT * E_DIM; // SPLITK * N_TOT * 128 floats

    // 1) drugF1 partials = drugFeatures @ W1 (split-K)
    gemm_big<N_D, F_SIZE><<<dim3((N_D + 63) / 64, SPLITK), 256, 0, stream>>>(
        drugF, W1, parts);
    // 2) x[0:6000] = relu( relu(sum parts + b1) @ W2 + b2 )
    gemm_small<<<dim3((N_D + 63) / 64), 256, 0, stream>>>(
        parts, SPLITK, (size_t)N_D * E_DIM, b1, W2, b2, x, N_D, 0);
    // 3) x[6000:7000] = embSe
    emb_copy<<<dim3((N_SE * E_DIM / 4 + 255) / 256), 256, 0, stream>>>(embSe, x);
    // 4) two propagation layers: x = HS( (A@x) @ Wl[i] + bl[i] )
    for (int l = 0; l < 2; l++) {
        gemm_big<N_TOT, N_TOT><<<dim3((N_TOT + 63) / 64, SPLITK), 256, 0, stream>>>(
            A, x, parts);
        gemm_small<<<dim3((N_TOT + 63) / 64), 256, 0, stream>>>(
            parts, SPLITK, (size_t)N_TOT * E_DIM, nullptr,
            Wl + (size_t)l * E_DIM * E_DIM, bl + (size_t)l * E_DIM, x, N_TOT, 1);
    }
    // 5) head
    final_mlp<<<dim3((M_TPL + 63) / 64), 256, 0, stream>>>(
        x, tpl, rsd, Wp1, bp1, Wp2, bp2, outp);
}

// Round 2
// 575.741 us; speedup vs baseline: 2.1755x; 2.1755x over previous
//
#include <hip/hip_runtime.h>
#include <hip/hip_bf16.h>

// Problem constants (from reference setup_inputs)
#define F_SIZE 1024
#define E_DIM  128
#define N_D    6000
#define N_SE   1000
#define N_TOT  7000
#define M_TPL  300000
#define LAMB   1e-6f
#define KPAD   7040   // N_TOT rounded up to multiple of 32 (xT leading dim)

typedef __bf16 bf16x8 __attribute__((ext_vector_type(8)));
typedef float  f32x4  __attribute__((ext_vector_type(4)));

__device__ __forceinline__ float hshrink(float v) {
    return fabsf(v) > LAMB ? v : 0.0f;
}

// RNE float -> bf16 bits (inputs are finite; no NaN handling needed)
__device__ __forceinline__ unsigned short f2bf(float f) {
    unsigned int u = __builtin_bit_cast(unsigned int, f);
    unsigned int r = u + 0x7fffu + ((u >> 16) & 1u);
    return (unsigned short)(r >> 16);
}

// ---------------------------------------------------------------------------
// fp32 tiled GEMM with split-K (used for MLP1 only):
// Cpart[sp][row][e] = sum_{k chunk} A[row][k]*B[k][e]. splits = gridDim.y.
// ---------------------------------------------------------------------------
template <int MROWS, int KDIM>
__global__ __launch_bounds__(256) void gemm_big(const float* __restrict__ A,
                                                const float* __restrict__ B,
                                                float* __restrict__ Cpart) {
    constexpr int BM = 64, BN = 128, BK = 16;
    constexpr int KT = (KDIM + BK - 1) / BK;
    __shared__ float As[BK][BM];
    __shared__ float Bs[BK][BN];

    const int tid = threadIdx.x;
    const int tn  = tid & 31;
    const int tm  = tid >> 5;
    const int row0 = blockIdx.x * BM;
    const int sp   = blockIdx.y;
    const int nsp  = gridDim.y;
    const int kt0 = (sp * KT) / nsp;
    const int kt1 = ((sp + 1) * KT) / nsp;

    float acc[8][4];
#pragma unroll
    for (int i = 0; i < 8; i++)
#pragma unroll
        for (int j = 0; j < 4; j++) acc[i][j] = 0.0f;

    const int lr = tid >> 2;
    const int lk = (tid & 3) * 4;
    const int grow = row0 + lr;

    for (int kt = kt0; kt < kt1; kt++) {
        const int k0 = kt * BK;
        __syncthreads();
        float4 av = make_float4(0.f, 0.f, 0.f, 0.f);
        if (grow < MROWS && (k0 + lk) < KDIM)
            av = *(const float4*)(A + (size_t)grow * KDIM + (k0 + lk));
        As[lk + 0][lr] = av.x;
        As[lk + 1][lr] = av.y;
        As[lk + 2][lr] = av.z;
        As[lk + 3][lr] = av.w;
        {
            int f  = tid;
            int bk = f >> 5, bn = (f & 31) * 4;
            float4 bv = make_float4(0.f, 0.f, 0.f, 0.f);
            if (k0 + bk < KDIM)
                bv = *(const float4*)(B + (size_t)(k0 + bk) * BN + bn);
            *(float4*)&Bs[bk][bn] = bv;
            f  = tid + 256;
            bk = f >> 5; bn = (f & 31) * 4;
            bv = make_float4(0.f, 0.f, 0.f, 0.f);
            if (k0 + bk < KDIM)
                bv = *(const float4*)(B + (size_t)(k0 + bk) * BN + bn);
            *(float4*)&Bs[bk][bn] = bv;
        }
        __syncthreads();
#pragma unroll
        for (int k = 0; k < BK; k++) {
            float4 a0 = *(const float4*)&As[k][tm * 8];
            float4 a1 = *(const float4*)&As[k][tm * 8 + 4];
            float4 bv = *(const float4*)&Bs[k][tn * 4];
            float a[8] = {a0.x, a0.y, a0.z, a0.w, a1.x, a1.y, a1.z, a1.w};
            float b[4] = {bv.x, bv.y, bv.z, bv.w};
#pragma unroll
            for (int i = 0; i < 8; i++)
#pragma unroll
                for (int j = 0; j < 4; j++) acc[i][j] += a[i] * b[j];
        }
    }

    float* outp = Cpart + (size_t)sp * MROWS * BN;
#pragma unroll
    for (int i = 0; i < 8; i++) {
        int r = row0 + tm * 8 + i;
        if (r < MROWS) {
            float4 v = make_float4(acc[i][0], acc[i][1], acc[i][2], acc[i][3]);
            *(float4*)(outp + (size_t)r * BN + tn * 4) = v;
        }
    }
}

// ---------------------------------------------------------------------------
// Small GEMM (K=128) fusing the split-K reduction of its A input.
// ---------------------------------------------------------------------------
__global__ __launch_bounds__(256) void gemm_small(const float* __restrict__ parts,
                                                  int nparts, size_t partStride,
                                                  const float* __restrict__ preBias,
                                                  const float* __restrict__ W,
                                                  const float* __restrict__ bias,
                                                  float* __restrict__ outp,
                                                  int Mrows, int act) {
    constexpr int BM = 64, BN = 128, BK = 16, KD = 128;
    __shared__ float As[BK][BM];
    __shared__ float Bs[BK][BN];

    const int tid = threadIdx.x;
    const int tn  = tid & 31;
    const int tm  = tid >> 5;
    const int row0 = blockIdx.x * BM;

    float acc[8][4];
#pragma unroll
    for (int i = 0; i < 8; i++)
#pragma unroll
        for (int j = 0; j < 4; j++) acc[i][j] = 0.0f;

    const int lr = tid >> 2;
    const int lk = (tid & 3) * 4;
    const int grow = row0 + lr;

    for (int kt = 0; kt < KD / BK; kt++) {
        const int k0 = kt * BK;
        __syncthreads();
        float4 av = make_float4(0.f, 0.f, 0.f, 0.f);
        if (grow < Mrows) {
            for (int s = 0; s < nparts; s++) {
                float4 p = *(const float4*)(parts + (size_t)s * partStride +
                                            (size_t)grow * KD + (k0 + lk));
                av.x += p.x; av.y += p.y; av.z += p.z; av.w += p.w;
            }
            if (preBias != nullptr) {
                float4 pb = *(const float4*)(preBias + k0 + lk);
                av.x = fmaxf(av.x + pb.x, 0.f);
                av.y = fmaxf(av.y + pb.y, 0.f);
                av.z = fmaxf(av.z + pb.z, 0.f);
                av.w = fmaxf(av.w + pb.w, 0.f);
            }
        }
        As[lk + 0][lr] = av.x;
        As[lk + 1][lr] = av.y;
        As[lk + 2][lr] = av.z;
        As[lk + 3][lr] = av.w;
        {
            int f  = tid;
            int bk = f >> 5, bn = (f & 31) * 4;
            *(float4*)&Bs[bk][bn] = *(const float4*)(W + (size_t)(k0 + bk) * BN + bn);
            f  = tid + 256;
            bk = f >> 5; bn = (f & 31) * 4;
            *(float4*)&Bs[bk][bn] = *(const float4*)(W + (size_t)(k0 + bk) * BN + bn);
        }
        __syncthreads();
#pragma unroll
        for (int k = 0; k < BK; k++) {
            float4 a0 = *(const float4*)&As[k][tm * 8];
            float4 a1 = *(const float4*)&As[k][tm * 8 + 4];
            float4 bv = *(const float4*)&Bs[k][tn * 4];
            float a[8] = {a0.x, a0.y, a0.z, a0.w, a1.x, a1.y, a1.z, a1.w};
            float b[4] = {bv.x, bv.y, bv.z, bv.w};
#pragma unroll
            for (int i = 0; i < 8; i++)
#pragma unroll
                for (int j = 0; j < 4; j++) acc[i][j] += a[i] * b[j];
        }
    }

    float4 bv = *(const float4*)(bias + tn * 4);
    float bb[4] = {bv.x, bv.y, bv.z, bv.w};
#pragma unroll
    for (int i = 0; i < 8; i++) {
        int r = row0 + tm * 8 + i;
        if (r < Mrows) {
            float v[4];
#pragma unroll
            for (int j = 0; j < 4; j++) {
                float u = acc[i][j] + bb[j];
                v[j] = act == 0 ? fmaxf(u, 0.f) : hshrink(u);
            }
            *(float4*)(outp + (size_t)r * BN + tn * 4) =
                make_float4(v[0], v[1], v[2], v[3]);
        }
    }
}

// ---------------------------------------------------------------------------
__global__ void emb_copy(const float* __restrict__ embSe, float* __restrict__ x) {
    int i = blockIdx.x * blockDim.x + threadIdx.x;
    if (i < N_SE * E_DIM / 4)
        ((float4*)(x + (size_t)N_D * E_DIM))[i] = ((const float4*)embSe)[i];
}

// ---------------------------------------------------------------------------
// x [N_TOT][128] fp32  ->  xT [128][KPAD] bf16 (rows >= N_TOT zero-filled)
// ---------------------------------------------------------------------------
__global__ __launch_bounds__(256) void transpose_x(const float* __restrict__ x,
                                                   unsigned short* __restrict__ xT) {
    __shared__ float t[64][65];
    const int r0 = blockIdx.x * 64;
    const int c0 = blockIdx.y * 64;
    const int tid = threadIdx.x;
    {
        const int i  = tid >> 4;          // 0..15
        const int cq = (tid & 15) * 4;
#pragma unroll
        for (int j = 0; j < 4; j++) {
            int r = r0 + i + j * 16;
            float4 v = make_float4(0.f, 0.f, 0.f, 0.f);
            if (r < N_TOT) v = *(const float4*)(x + (size_t)r * E_DIM + c0 + cq);
            t[i + j * 16][cq + 0] = v.x;
            t[i + j * 16][cq + 1] = v.y;
            t[i + j * 16][cq + 2] = v.z;
            t[i + j * 16][cq + 3] = v.w;
        }
    }
    __syncthreads();
    {
        const int ci = tid >> 2;          // 0..63
        const int rq = (tid & 3) * 16;
        unsigned short us[16];
#pragma unroll
        for (int j = 0; j < 16; j++) us[j] = f2bf(t[rq + j][ci]);
        unsigned short* dst = xT + (size_t)(c0 + ci) * KPAD + r0 + rq;
        *(uint4*)dst       = *(uint4*)&us[0];
        *(uint4*)(dst + 8) = *(uint4*)&us[8];
    }
}

// ---------------------------------------------------------------------------
// Wp1 [384][128] fp32 -> Wp1T [128][384] bf16
// ---------------------------------------------------------------------------
__global__ void conv_wp1t(const float* __restrict__ Wp1,
                          unsigned short* __restrict__ Wp1T) {
    int idx = blockIdx.x * 256 + threadIdx.x;   // idx = n*384 + k
    if (idx < 128 * 384) {
        int n = idx / 384, k = idx - n * 384;
        Wp1T[idx] = f2bf(Wp1[(size_t)k * 128 + n]);
    }
}

// ---------------------------------------------------------------------------
// bf16 MFMA split-K GEMM for A@x:
// Cpart[sp][row][n] = sum_{k chunk} A[row][k] * x[k][n]
// A fp32 (converted during staging), x supplied transposed bf16 xT[n][k].
// 128x128 tile, BK=32, 4 waves each computing 64x64 via 4x4 16x16x32 MFMAs.
// LDS rows padded to 40 bf16 (80 B) -> only 2-way bank aliasing (free).
// ---------------------------------------------------------------------------
__global__ __launch_bounds__(256) void gemm_ax_bf16(const float* __restrict__ A,
                                                    const unsigned short* __restrict__ xT,
                                                    float* __restrict__ Cpart) {
    __shared__ unsigned short As[128 * 40];
    __shared__ unsigned short Bs[128 * 40];

    const int tid = threadIdx.x;
    const int row0 = blockIdx.x * 128;
    const int sp = blockIdx.y, nsp = gridDim.y;
    const int KT = (N_TOT + 31) / 32;               // 219 k-tiles
    const int kt0 = (sp * KT) / nsp;
    const int kt1 = ((sp + 1) * KT) / nsp;

    const int mrow = tid >> 1;                      // 0..127
    const int kq   = (tid & 1) * 16;                // 0 or 16
    const bool mok = (row0 + mrow) < N_TOT;
    const float* aBase = A + (size_t)(row0 + mrow) * N_TOT;
    const unsigned short* bBase = xT + (size_t)mrow * KPAD;

    const int lane = tid & 63;
    const int w  = tid >> 6;
    const int wm = (w & 1) * 64;
    const int wn = (w >> 1) * 64;
    const int fm = lane & 15;
    const int ko = (lane >> 4) * 8;

    const f32x4 zero = {0.f, 0.f, 0.f, 0.f};
    f32x4 acc[4][4];
#pragma unroll
    for (int i = 0; i < 4; i++)
#pragma unroll
        for (int j = 0; j < 4; j++) acc[i][j] = zero;

    for (int kt = kt0; kt < kt1; kt++) {
        const int k0 = kt * 32;
        __syncthreads();
        // ---- A tile: fp32 load + cvt -> As[m][k] ----
        {
            unsigned short us[16];
#pragma unroll
            for (int j = 0; j < 4; j++) {
                float4 v = make_float4(0.f, 0.f, 0.f, 0.f);
                int k = k0 + kq + 4 * j;
                if (mok && k < N_TOT) v = *(const float4*)(aBase + k);
                us[4 * j + 0] = f2bf(v.x);
                us[4 * j + 1] = f2bf(v.y);
                us[4 * j + 2] = f2bf(v.z);
                us[4 * j + 3] = f2bf(v.w);
            }
            *(uint4*)&As[mrow * 40 + kq]     = *(uint4*)&us[0];
            *(uint4*)&As[mrow * 40 + kq + 8] = *(uint4*)&us[8];
        }
        // ---- B tile: bf16 copy xT[n][k0..k0+32) -> Bs[n][k] ----
        {
            const uint4* src = (const uint4*)(bBase + k0 + kq);
            uint4 b0 = src[0];
            uint4 b1 = src[1];
            *(uint4*)&Bs[mrow * 40 + kq]     = b0;
            *(uint4*)&Bs[mrow * 40 + kq + 8] = b1;
        }
        __syncthreads();
        bf16x8 af[4], bfv[4];
#pragma unroll
        for (int i = 0; i < 4; i++) {
            af[i]  = *(const bf16x8*)&As[(wm + i * 16 + fm) * 40 + ko];
            bfv[i] = *(const bf16x8*)&Bs[(wn + i * 16 + fm) * 40 + ko];
        }
#pragma unroll
        for (int mi = 0; mi < 4; mi++)
#pragma unroll
            for (int ni = 0; ni < 4; ni++)
                acc[mi][ni] = __builtin_amdgcn_mfma_f32_16x16x32_bf16(
                    af[mi], bfv[ni], acc[mi][ni], 0, 0, 0);
    }

    float* op = Cpart + (size_t)sp * N_TOT * E_DIM;
#pragma unroll
    for (int mi = 0; mi < 4; mi++) {
#pragma unroll
        for (int r = 0; r < 4; r++) {
            int row = row0 + wm + mi * 16 + (lane >> 4) * 4 + r;
            if (row < N_TOT) {
#pragma unroll
                for (int ni = 0; ni < 4; ni++)
                    op[(size_t)row * E_DIM + wn + ni * 16 + fm] = acc[mi][ni][r];
            }
        }
    }
}

// ---------------------------------------------------------------------------
// Head: 128 triples/block. Gather h[128][384] (rsqrtdeg-scaled x rows, cvt to
// bf16 in LDS), MFMA vs Wp1T, fused hardshrink->dot(Wp2)->hardshrink epilogue.
// ---------------------------------------------------------------------------
__global__ __launch_bounds__(256) void head_bf16(const float* __restrict__ X,
                                                 const int* __restrict__ tpl,
                                                 const float* __restrict__ rsd,
                                                 const unsigned short* __restrict__ Wp1T,
                                                 const float* __restrict__ bp1,
                                                 const float* __restrict__ Wp2,
                                                 const float* __restrict__ bp2,
                                                 float* __restrict__ outp) {
    __shared__ unsigned short As[128 * 40];
    __shared__ unsigned short Bs[128 * 40];
    __shared__ int   ridx[128][3];
    __shared__ float rscale[128][3];
    __shared__ float sred[2][128];

    const int tid = threadIdx.x;
    const int m0  = blockIdx.x * 128;

    for (int i = tid; i < 384; i += 256) {
        int m = i / 3, s = i - m * 3;
        int gm = m0 + m;
        int r = 0; float sc = 0.f;
        if (gm < M_TPL) { r = tpl[gm * 3 + s]; sc = rsd[r]; }
        ridx[m][s] = r;
        rscale[m][s] = sc;
    }

    const int mrow = tid >> 1;
    const int kq   = (tid & 1) * 16;
    const int lane = tid & 63;
    const int w  = tid >> 6;
    const int wm = (w & 1) * 64;
    const int wn = (w >> 1) * 64;
    const int fm = lane & 15;
    const int ko = (lane >> 4) * 8;

    const f32x4 zero = {0.f, 0.f, 0.f, 0.f};
    f32x4 acc[4][4];
#pragma unroll
    for (int i = 0; i < 4; i++)
#pragma unroll
        for (int j = 0; j < 4; j++) acc[i][j] = zero;

    for (int kt = 0; kt < 12; kt++) {
        __syncthreads();   // kt==0 also covers ridx/rscale staging
        // ---- A tile: gathered, scaled, cvt ----
        {
            const int seg  = kt >> 2;
            const int kcol = (kt & 3) * 32 + kq;
            int   r  = ridx[mrow][seg];
            float sc = rscale[mrow][seg];
            const float* xp = X + (size_t)r * E_DIM + kcol;
            unsigned short us[16];
#pragma unroll
            for (int j = 0; j < 4; j++) {
                float4 v = *(const float4*)(xp + 4 * j);
                us[4 * j + 0] = f2bf(v.x * sc);
                us[4 * j + 1] = f2bf(v.y * sc);
                us[4 * j + 2] = f2bf(v.z * sc);
                us[4 * j + 3] = f2bf(v.w * sc);
            }
            *(uint4*)&As[mrow * 40 + kq]     = *(uint4*)&us[0];
            *(uint4*)&As[mrow * 40 + kq + 8] = *(uint4*)&us[8];
        }
        // ---- B tile from Wp1T ----
        {
            const uint4* src = (const uint4*)(Wp1T + (size_t)mrow * 384 + kt * 32 + kq);
            uint4 b0 = src[0];
            uint4 b1 = src[1];
            *(uint4*)&Bs[mrow * 40 + kq]     = b0;
            *(uint4*)&Bs[mrow * 40 + kq + 8] = b1;
        }
        __syncthreads();
        bf16x8 af[4], bfv[4];
#pragma unroll
        for (int i = 0; i < 4; i++) {
            af[i]  = *(const bf16x8*)&As[(wm + i * 16 + fm) * 40 + ko];
            bfv[i] = *(const bf16x8*)&Bs[(wn + i * 16 + fm) * 40 + ko];
        }
#pragma unroll
        for (int mi = 0; mi < 4; mi++)
#pragma unroll
            for (int ni = 0; ni < 4; ni++)
                acc[mi][ni] = __builtin_amdgcn_mfma_f32_16x16x32_bf16(
                    af[mi], bfv[ni], acc[mi][ni], 0, 0, 0);
    }

    // ---- epilogue: u=HS(acc+bp1); s=sum_n u*Wp2[n]; out=HS(s+bp2) ----
    float bp1v[4], wp2v[4];
#pragma unroll
    for (int ni = 0; ni < 4; ni++) {
        int n = wn + ni * 16 + fm;
        bp1v[ni] = bp1[n];
        wp2v[ni] = Wp2[n];
    }
#pragma unroll
    for (int mi = 0; mi < 4; mi++) {
#pragma unroll
        for (int r = 0; r < 4; r++) {
            float p = 0.f;
#pragma unroll
            for (int ni = 0; ni < 4; ni++)
                p += hshrink(acc[mi][ni][r] + bp1v[ni]) * wp2v[ni];
            p += __shfl_xor(p, 1, 64);
            p += __shfl_xor(p, 2, 64);
            p += __shfl_xor(p, 4, 64);
            p += __shfl_xor(p, 8, 64);
            if (fm == 0)
                sred[wn >> 6][wm + mi * 16 + (lane >> 4) * 4 + r] = p;
        }
    }
    __syncthreads();
    if (tid < 128) {
        int gm = m0 + tid;
        if (gm < M_TPL)
            outp[gm] = hshrink(sred[0][tid] + sred[1][tid] + bp2[0]);
    }
}

// ---------------------------------------------------------------------------
extern "C" void kernel_launch(void* const* d_in, const int* in_sizes, int n_in,
                              void* d_out, int out_size, void* d_ws, size_t ws_size,
                              hipStream_t stream) {
    const float* drugF = (const float*)d_in[0];
    const float* A     = (const float*)d_in[1];
    const int*   tpl   = (const int*)d_in[2];
    const float* rsd   = (const float*)d_in[3];
    const float* W1    = (const float*)d_in[4];
    const float* b1    = (const float*)d_in[5];
    const float* W2    = (const float*)d_in[6];
    const float* b2    = (const float*)d_in[7];
    const float* embSe = (const float*)d_in[8];
    const float* Wl    = (const float*)d_in[9];
    const float* bl    = (const float*)d_in[10];
    const float* Wp1   = (const float*)d_in[11];
    const float* bp1   = (const float*)d_in[12];
    const float* Wp2   = (const float*)d_in[13];
    const float* bp2   = (const float*)d_in[14];
    float* outp = (float*)d_out;

    float* ws = (float*)d_ws;
    const size_t XSZ = (size_t)N_TOT * E_DIM;   // 896000 floats
    // choose split-K count by workspace capacity (same every call)
    int SPL = 2;
    {
        const size_t bfBytes = (size_t)128 * KPAD * 2 + (size_t)128 * 384 * 2;
        if (ws_size >= (XSZ * (1 + 8)) * 4 + bfBytes) SPL = 8;
        else if (ws_size >= (XSZ * (1 + 4)) * 4 + bfBytes) SPL = 4;
    }
    float* x     = ws;
    float* parts = ws + XSZ;
    unsigned short* xT   = (unsigned short*)(ws + XSZ * (1 + (size_t)SPL));
    unsigned short* Wp1T = xT + (size_t)128 * KPAD;

    // 1) MLP layer 1 (fp32 split-K) + fused-reduce MLP layer 2
    gemm_big<N_D, F_SIZE><<<dim3((N_D + 63) / 64, SPL), 256, 0, stream>>>(
        drugF, W1, parts);
    gemm_small<<<dim3((N_D + 63) / 64), 256, 0, stream>>>(
        parts, SPL, (size_t)N_D * E_DIM, b1, W2, b2, x, N_D, 0);
    // 2) embSe rows
    emb_copy<<<dim3((N_SE * E_DIM / 4 + 255) / 256), 256, 0, stream>>>(embSe, x);
    // 3) Wp1 transpose+convert (any time before head)
    conv_wp1t<<<dim3(192), 256, 0, stream>>>(Wp1, Wp1T);
    // 4) two propagation layers: x = HS( (A@x) @ Wl[i] + bl[i] )
    for (int l = 0; l < 2; l++) {
        transpose_x<<<dim3(KPAD / 64, 2), 256, 0, stream>>>(x, xT);
        gemm_ax_bf16<<<dim3((N_TOT + 127) / 128, SPL), 256, 0, stream>>>(
            A, xT, parts);
        gemm_small<<<dim3((N_TOT + 63) / 64), 256, 0, stream>>>(
            parts, SPL, XSZ, nullptr,
            Wl + (size_t)l * E_DIM * E_DIM, bl + (size_t)l * E_DIM, x, N_TOT, 1);
    }
    // 5) head
    head_bf16<<<dim3((M_TPL + 127) / 128), 256, 0, stream>>>(
        x, tpl, rsd, Wp1T, bp1, Wp2, bp2, outp);
}